// Round 1
// baseline (660.656 us; speedup 1.0000x reference)
//
#include <hip/hip_runtime.h>

// SoftDecisionTree: BATCH=1M rows, DIM=64, DEPTH=7 -> 127 internal nodes, 128 leaves.
// One thread per batch row. x row held in 16 v4f registers; weights/bias/leaf are
// wave-uniform -> scalar loads (s_load) broadcast via the scalar cache.
// Tree walked depth-first via template recursion: stack is (prob, p) per level
// = ~14 VGPRs, all indices compile-time (no scratch spills).

typedef float v4f __attribute__((ext_vector_type(4)));

constexpr int DIM = 64;
constexpr int N_LEAVES = 128;
constexpr int BATCH = 1 << 20;

__device__ __forceinline__ float fast_sigmoid(float z) {
    // 1/(1+exp(-z)) = rcp(1 + exp2(-z*log2(e)))
    float e = __builtin_amdgcn_exp2f(z * -1.44269504088896340736f);
    return __builtin_amdgcn_rcpf(1.0f + e);
}

__device__ __forceinline__ float dot64(const v4f xv[16], const float* __restrict__ wrow) {
    const v4f* w4 = (const v4f*)wrow;  // wave-uniform address -> s_load
    v4f a0 = xv[0] * w4[0];
    v4f a1 = xv[1] * w4[1];
    v4f a2 = xv[2] * w4[2];
    v4f a3 = xv[3] * w4[3];
#pragma unroll
    for (int i = 4; i < 16; i += 4) {
        a0 += xv[i + 0] * w4[i + 0];   // fp-contract -> v_pk_fma_f32
        a1 += xv[i + 1] * w4[i + 1];
        a2 += xv[i + 2] * w4[i + 2];
        a3 += xv[i + 3] * w4[i + 3];
    }
    v4f s = (a0 + a1) + (a2 + a3);
    return (s.x + s.y) + (s.z + s.w);
}

template <int NODE, int DEPTH>
struct Walk {
    __device__ __forceinline__ static void run(
        float prob, const v4f xv[16],
        const float* __restrict__ w, const float* __restrict__ bias,
        const float* __restrict__ leaf,
        v4f* __restrict__ out4, v4f& cur, float& pred)
    {
        float z = dot64(xv, w + NODE * DIM) + bias[NODE];
        float p = fast_sigmoid(z);
        Walk<2 * NODE + 1, DEPTH + 1>::run(prob * (1.0f - p), xv, w, bias, leaf, out4, cur, pred);
        Walk<2 * NODE + 2, DEPTH + 1>::run(prob * p,          xv, w, bias, leaf, out4, cur, pred);
    }
};

// Leaf specialization (DEPTH == 7): NODE in [127, 254], leaf index = NODE - 127.
template <int NODE>
struct Walk<NODE, 7> {
    __device__ __forceinline__ static void run(
        float prob, const v4f*,
        const float* __restrict__, const float* __restrict__,
        const float* __restrict__ leaf,
        v4f* __restrict__ out4, v4f& cur, float& pred)
    {
        constexpr int LI = NODE - 127;
        cur[LI & 3] = prob;                      // compile-time lane of the float4
        pred = fmaf(prob, leaf[LI], pred);       // leaf[LI]: uniform scalar load
        if constexpr ((LI & 3) == 3) {
            out4[LI >> 2] = cur;                 // 16B store, offsets 0..2032B from row base
        }
    }
};

__global__ __launch_bounds__(256) void sdt_kernel(
    const float* __restrict__ x,
    const float* __restrict__ w,
    const float* __restrict__ bias,
    const float* __restrict__ leaf,
    float* __restrict__ pred_out,
    float* __restrict__ lp_out)
{
    const int row = blockIdx.x * 256 + threadIdx.x;

    const v4f* xg = (const v4f*)(x + (size_t)row * DIM);
    v4f xv[16];
#pragma unroll
    for (int i = 0; i < 16; ++i) xv[i] = xg[i];   // 16x global_load_dwordx4

    v4f* out4 = (v4f*)(lp_out + (size_t)row * N_LEAVES);
    v4f cur;
    float pred = 0.0f;

    Walk<0, 0>::run(1.0f, xv, w, bias, leaf, out4, cur, pred);

    pred_out[row] = pred;                          // coalesced
}

extern "C" void kernel_launch(void* const* d_in, const int* in_sizes, int n_in,
                              void* d_out, int out_size, void* d_ws, size_t ws_size,
                              hipStream_t stream) {
    const float* x    = (const float*)d_in[0];
    const float* w    = (const float*)d_in[1];
    const float* bias = (const float*)d_in[2];
    const float* leaf = (const float*)d_in[3];

    float* pred = (float*)d_out;             // BATCH floats
    float* lp   = (float*)d_out + BATCH;     // BATCH x 128 floats

    sdt_kernel<<<BATCH / 256, 256, 0, stream>>>(x, w, bias, leaf, pred, lp);
}

// Round 2
// 289.272 us; speedup vs baseline: 2.2839x; 2.2839x over previous
//
#include <hip/hip_runtime.h>

// SoftDecisionTree: BATCH=1M rows, DIM=64, DEPTH=7 -> 127 internal nodes, 128 leaves.
// One thread per batch row; x row in 16 float4 VGPRs; weights/bias/leaf wave-uniform
// (scalar loads). Tree walked depth-first via template recursion (all indices
// compile-time, no scratch).
//
// Round-2 change: leaf_probs writes go through per-wave LDS staging so every HBM
// write is a full 128B line (round 1 showed 4.5x write amplification from
// 16B-per-lane scattered stores). Per depth-2 subtree (32 leaves = 128B/row),
// lanes write LDS [j][row] (conflict-free), then the wave flushes 64 rows with
// 8 full-line nontemporal store instructions. No barriers: wave-synchronous,
// same-wave DS ops are in-order, lgkmcnt(0) before reads.

typedef float v4f __attribute__((ext_vector_type(4)));

constexpr int DIM = 64;
constexpr int BATCH = 1 << 20;

__device__ __forceinline__ float fast_sigmoid(float z) {
    float e = __builtin_amdgcn_exp2f(z * -1.44269504088896340736f);
    return __builtin_amdgcn_rcpf(1.0f + e);
}

__device__ __forceinline__ float dot64(const v4f xv[16], const float* __restrict__ wrow) {
    const v4f* w4 = (const v4f*)wrow;  // wave-uniform -> s_load broadcast
    v4f a0 = xv[0] * w4[0];
    v4f a1 = xv[1] * w4[1];
    v4f a2 = xv[2] * w4[2];
    v4f a3 = xv[3] * w4[3];
#pragma unroll
    for (int i = 4; i < 16; i += 4) {
        a0 += xv[i + 0] * w4[i + 0];
        a1 += xv[i + 1] * w4[i + 1];
        a2 += xv[i + 2] * w4[i + 2];
        a3 += xv[i + 3] * w4[i + 3];
    }
    v4f s = (a0 + a1) + (a2 + a3);
    return (s.x + s.y) + (s.z + s.w);
}

struct Ctx {
    const float* __restrict__ w;
    const float* __restrict__ bias;
    const float* __restrict__ leaf;
    v4f* __restrict__ lds;        // this wave's region: [8 j][64 row] float4
    float* __restrict__ out_row0; // lp_out + wave_row0 * 128
    int lane;
    float pred;
};

// Flush one depth-2 subtree chunk (32 floats/row, 128B) for all 64 rows of the wave.
// Each global_store_dwordx4 instruction covers 8 complete 128B lines.
template <int C>
__device__ __forceinline__ void flush_chunk(Ctx& c) {
    asm volatile("s_waitcnt lgkmcnt(0)" ::: "memory");  // all lanes' LDS writes done
    const int j = c.lane & 7;
    const int rsub = c.lane >> 3;
#pragma unroll
    for (int i = 0; i < 8; ++i) {
        v4f v = c.lds[(size_t)j * 64 + i * 8 + rsub];
        v4f* dst = (v4f*)(c.out_row0 + (size_t)(i * 8 + rsub) * 128 + C * 32) + j;
        __builtin_nontemporal_store(v, dst);  // full-line, don't pollute L3 (keep x resident)
    }
    asm volatile("" ::: "memory");  // don't let next chunk's LDS writes hoist above reads
}

template <int NODE, int DEPTH>
struct Walk {
    __device__ __forceinline__ static void run(float prob, const v4f xv[16], Ctx& c, v4f& cur) {
        float z = dot64(xv, c.w + NODE * DIM) + c.bias[NODE];
        float p = fast_sigmoid(z);
        Walk<2 * NODE + 1, DEPTH + 1>::run(prob * (1.0f - p), xv, c, cur);
        Walk<2 * NODE + 2, DEPTH + 1>::run(prob * p,          xv, c, cur);
    }
};

// Leaf specialization (DEPTH == 7): NODE in [127, 254], leaf index LI = NODE - 127.
template <int NODE>
struct Walk<NODE, 7> {
    __device__ __forceinline__ static void run(float prob, const v4f*, Ctx& c, v4f& cur) {
        constexpr int LI = NODE - 127;
        cur[LI & 3] = prob;                         // compile-time lane of the float4
        c.pred = fmaf(prob, c.leaf[LI], c.pred);    // uniform scalar load
        if constexpr ((LI & 3) == 3) {
            constexpr int J = (LI >> 2) & 7;
            c.lds[(size_t)J * 64 + c.lane] = cur;   // ds_write_b128, contiguous 16B/lane
        }
        if constexpr ((LI & 31) == 31) {
            flush_chunk<(LI >> 5)>(c);
        }
    }
};

__global__ __launch_bounds__(256) void sdt_kernel(
    const float* __restrict__ x,
    const float* __restrict__ w,
    const float* __restrict__ bias,
    const float* __restrict__ leaf,
    float* __restrict__ pred_out,
    float* __restrict__ lp_out)
{
    const int lane = threadIdx.x & 63;
    const int wave = threadIdx.x >> 6;
    const int row  = blockIdx.x * 256 + threadIdx.x;
    const int wave_row0 = blockIdx.x * 256 + wave * 64;

    __shared__ v4f lds4[4][8][64];   // 32 KB: [wave][j][row]

    const v4f* xg = (const v4f*)(x + (size_t)row * DIM);
    v4f xv[16];
#pragma unroll
    for (int i = 0; i < 16; ++i) xv[i] = xg[i];

    Ctx c{w, bias, leaf, &lds4[wave][0][0],
          lp_out + (size_t)wave_row0 * 128, lane, 0.0f};
    v4f cur;

    Walk<0, 0>::run(1.0f, xv, c, cur);

    pred_out[row] = c.pred;
}

extern "C" void kernel_launch(void* const* d_in, const int* in_sizes, int n_in,
                              void* d_out, int out_size, void* d_ws, size_t ws_size,
                              hipStream_t stream) {
    const float* x    = (const float*)d_in[0];
    const float* w    = (const float*)d_in[1];
    const float* bias = (const float*)d_in[2];
    const float* leaf = (const float*)d_in[3];

    float* pred = (float*)d_out;             // BATCH floats
    float* lp   = (float*)d_out + BATCH;     // BATCH x 128 floats

    sdt_kernel<<<BATCH / 256, 256, 0, stream>>>(x, w, bias, leaf, pred, lp);
}